// Round 1
// baseline (199.317 us; speedup 1.0000x reference)
//
#include <hip/hip_runtime.h>
#include <hip/hip_bf16.h>

// Problem constants (fixed by reference setup_inputs):
//   u_predict: [B=64][NL=2048][NH=32][D=16] f32  (256 MB)
//   b:         [NL=2048][NH=32] f32
//   out v:     [B=64][NH=32][D=16] f32 (32768 floats)
#define B_  64
#define NL_ 2048
#define NH_ 32
#define D_  16
#define HD_ 512            // NH_*D_
#define LCHUNK 64          // l's per block
#define NCHUNK (NL_/LCHUNK)  // 32

// Fused routing pass: per (b,l) tile compute logits (+ optional dot with vsum),
// softmax over h (32), accumulate c*u into per-(b,chunk) partial s.
// Lane mapping (64 lanes): load A = elements [4*lane, 4*lane+4)  -> h0 = lane>>2 in [0,16), d = (lane&3)*4
//                          load Bq = elements [256+4*lane, ...)  -> h1 = h0+16,          same d slice
template<bool ADD_DOT>
__global__ __launch_bounds__(256) void pass_kernel(const float* __restrict__ u,
                                                   const float* __restrict__ blog,
                                                   const float* __restrict__ vsum,
                                                   float* __restrict__ partial_s)
{
    const int b     = blockIdx.y;
    const int chunk = blockIdx.x;
    const int tid   = threadIdx.x;
    const int wave  = tid >> 6;
    const int lane  = tid & 63;
    const int h0    = lane >> 2;          // 0..15
    const int h1    = h0 + 16;            // 16..31
    const int dq    = (lane & 3) << 2;    // 0,4,8,12

    float4 vA = {0.f,0.f,0.f,0.f}, vB = {0.f,0.f,0.f,0.f};
    if (ADD_DOT) {
        vA = *(const float4*)(vsum + b*HD_ + h0*D_ + dq);
        vB = *(const float4*)(vsum + b*HD_ + h1*D_ + dq);
    }

    float4 accA = {0.f,0.f,0.f,0.f};
    float4 accB = {0.f,0.f,0.f,0.f};

    const int l0 = chunk*LCHUNK + wave*(LCHUNK/4);   // 16 l's per wave

    for (int j = 0; j < LCHUNK/4; ++j) {
        const int l = l0 + j;
        const float* up = u + ((size_t)b*NL_ + l)*HD_;
        const float4 a  = *(const float4*)(up + 4*lane);         // h0 slice
        const float4 bq = *(const float4*)(up + 256 + 4*lane);   // h1 slice

        float la = blog[l*NH_ + h0];
        float lb = blog[l*NH_ + h1];

        if (ADD_DOT) {
            float da = a.x*vA.x + a.y*vA.y + a.z*vA.z + a.w*vA.w;
            float db = bq.x*vB.x + bq.y*vB.y + bq.z*vB.z + bq.w*vB.w;
            // full dot over d=16: combine the 4 lanes of this h-group
            da += __shfl_xor(da, 1); da += __shfl_xor(da, 2);
            db += __shfl_xor(db, 1); db += __shfl_xor(db, 2);
            la += da; lb += db;
        }

        // softmax over 32 h, replicated 4x across the 64 lanes
        float m = fmaxf(la, lb);
        #pragma unroll
        for (int off = 1; off < 64; off <<= 1) m = fmaxf(m, __shfl_xor(m, off));
        const float ea = __expf(la - m);
        const float eb = __expf(lb - m);
        float ssum = ea + eb;
        #pragma unroll
        for (int off = 1; off < 64; off <<= 1) ssum += __shfl_xor(ssum, off);
        const float inv = 4.0f / ssum;    // each h counted 4x in ssum
        const float ca = ea * inv;
        const float cb = eb * inv;

        accA.x += ca*a.x;  accA.y += ca*a.y;  accA.z += ca*a.z;  accA.w += ca*a.w;
        accB.x += cb*bq.x; accB.y += cb*bq.y; accB.z += cb*bq.z; accB.w += cb*bq.w;
    }

    // block-level reduction of the 4 waves' accumulators
    __shared__ float sred[4][HD_];
    float* dst = &sred[wave][0];
    dst[4*lane+0]       = accA.x; dst[4*lane+1]       = accA.y;
    dst[4*lane+2]       = accA.z; dst[4*lane+3]       = accA.w;
    dst[256+4*lane+0]   = accB.x; dst[256+4*lane+1]   = accB.y;
    dst[256+4*lane+2]   = accB.z; dst[256+4*lane+3]   = accB.w;
    __syncthreads();

    float r0 = sred[0][tid]     + sred[1][tid]     + sred[2][tid]     + sred[3][tid];
    float r1 = sred[0][tid+256] + sred[1][tid+256] + sred[2][tid+256] + sred[3][tid+256];
    float* pout = partial_s + ((size_t)b*NCHUNK + chunk)*HD_;
    pout[tid]       = r0;
    pout[tid + 256] = r1;
}

// Reduce partials over chunks, apply Hinton squash per (b,h), update vsum / write out.
// MODE 0: vsum = v (first iteration);  MODE 1: vsum += v;  MODE 2: write d_out only.
template<int MODE>
__global__ __launch_bounds__(512) void squash_kernel(const float* __restrict__ partial_s,
                                                     float* __restrict__ vsum,
                                                     float* __restrict__ out)
{
    const int b = blockIdx.x;
    const int t = threadIdx.x;            // t = h*16 + d
    const float* p = partial_s + (size_t)b*NCHUNK*HD_ + t;
    float s = 0.f;
    #pragma unroll
    for (int c = 0; c < NCHUNK; ++c) s += p[c*HD_];

    // ||s||^2 over d=16: lanes t..t+15 share h (16 divides 64)
    float sq = s*s;
    sq += __shfl_xor(sq, 1); sq += __shfl_xor(sq, 2);
    sq += __shfl_xor(sq, 4); sq += __shfl_xor(sq, 8);

    const float scale = sq / ((1.0f + sq) * sqrtf(sq + 1e-8f));
    const float v = s * scale;

    if (MODE == 0)      vsum[b*HD_ + t]  = v;
    else if (MODE == 1) vsum[b*HD_ + t] += v;
    else                out[b*HD_ + t]   = v;
}

extern "C" void kernel_launch(void* const* d_in, const int* in_sizes, int n_in,
                              void* d_out, int out_size, void* d_ws, size_t ws_size,
                              hipStream_t stream)
{
    const float* u    = (const float*)d_in[0];   // [64][2048][32][16]
    const float* blog = (const float*)d_in[1];   // [2048][32]
    float* out        = (float*)d_out;           // [64][32][16]

    // workspace: partials [64][32][512] (4 MB) + vsum [64][512] (128 KB)
    float* partial_s = (float*)d_ws;
    float* vsum      = partial_s + (size_t)B_*NCHUNK*HD_;

    dim3 grid(NCHUNK, B_);
    dim3 block(256);

    // pass 0: c = softmax(b) (no agreement term), v0 = squash(s)
    pass_kernel<false><<<grid, block, 0, stream>>>(u, blog, vsum, partial_s);
    squash_kernel<0><<<B_, 512, 0, stream>>>(partial_s, vsum, out);

    // iterations 1..3; logits = b + u.(v0+...+v_{t-1}) by linearity
    pass_kernel<true><<<grid, block, 0, stream>>>(u, blog, vsum, partial_s);
    squash_kernel<1><<<B_, 512, 0, stream>>>(partial_s, vsum, out);

    pass_kernel<true><<<grid, block, 0, stream>>>(u, blog, vsum, partial_s);
    squash_kernel<1><<<B_, 512, 0, stream>>>(partial_s, vsum, out);

    pass_kernel<true><<<grid, block, 0, stream>>>(u, blog, vsum, partial_s);
    squash_kernel<2><<<B_, 512, 0, stream>>>(partial_s, vsum, out);
}

// Round 2
// 160.258 us; speedup vs baseline: 1.2437x; 1.2437x over previous
//
#include <hip/hip_runtime.h>
#include <hip/hip_fp16.h>
#include <hip/hip_bf16.h>

// Problem constants (fixed by reference setup_inputs):
//   u_predict: [B=64][NL=2048][NH=32][D=16] f32  (256 MB)
//   b:         [NL=2048][NH=32] f32
//   out v:     [B=64][NH=32][D=16] f32
#define B_  64
#define NL_ 2048
#define NH_ 32
#define D_  16
#define HD_ 512              // NH_*D_
#define LCHUNK 64            // l's per block
#define NCHUNK (NL_/LCHUNK)  // 32

union H4 { uint2 u2; __half2 h2[2]; };
union H8 { uint4 u4; __half2 h2[4]; };

// ---------------- pass 0: f32 read, c0 = softmax(b) (no agreement), fp16 copy emit ----
__global__ __launch_bounds__(256) void pass0_kernel(const float* __restrict__ u,
                                                    const float* __restrict__ blog,
                                                    __half* __restrict__ u16,
                                                    float* __restrict__ partial_s)
{
    const int b     = blockIdx.y;
    const int chunk = blockIdx.x;
    const int tid   = threadIdx.x;
    const int wave  = tid >> 6;
    const int lane  = tid & 63;
    const int h0    = lane >> 2;          // 0..15
    const int h1    = h0 + 16;

    float4 accA = {0.f,0.f,0.f,0.f};
    float4 accB = {0.f,0.f,0.f,0.f};

    const int l0 = chunk*LCHUNK + wave*(LCHUNK/4);

    for (int j = 0; j < LCHUNK/4; ++j) {
        const int l = l0 + j;
        const size_t base = ((size_t)b*NL_ + l)*HD_;
        const float4 a  = *(const float4*)(u + base + 4*lane);
        const float4 bq = *(const float4*)(u + base + 256 + 4*lane);

        // emit fp16 copy (same [b][l][h][d] layout)
        H4 ha, hb;
        ha.h2[0] = __floats2half2_rn(a.x, a.y);   ha.h2[1] = __floats2half2_rn(a.z, a.w);
        hb.h2[0] = __floats2half2_rn(bq.x, bq.y); hb.h2[1] = __floats2half2_rn(bq.z, bq.w);
        *(uint2*)((__half*)u16 + base + 4*lane)       = ha.u2;
        *(uint2*)((__half*)u16 + base + 256 + 4*lane) = hb.u2;

        float la = blog[l*NH_ + h0];
        float lb = blog[l*NH_ + h1];

        // softmax over 32 h; values depend on lane>>2 only -> skip off=1,2
        float m = fmaxf(la, lb);
        #pragma unroll
        for (int off = 4; off < 64; off <<= 1) m = fmaxf(m, __shfl_xor(m, off));
        const float ea = __expf(la - m);
        const float eb = __expf(lb - m);
        float ssum = ea + eb;
        #pragma unroll
        for (int off = 4; off < 64; off <<= 1) ssum += __shfl_xor(ssum, off);
        const float inv = 1.0f / ssum;       // each h counted once over the 16 groups
        const float ca = ea * inv;
        const float cb = eb * inv;

        accA.x += ca*a.x;  accA.y += ca*a.y;  accA.z += ca*a.z;  accA.w += ca*a.w;
        accB.x += cb*bq.x; accB.y += cb*bq.y; accB.z += cb*bq.z; accB.w += cb*bq.w;
    }

    __shared__ float sred[4][HD_];
    float* dst = &sred[wave][0];
    dst[4*lane+0]     = accA.x; dst[4*lane+1]     = accA.y;
    dst[4*lane+2]     = accA.z; dst[4*lane+3]     = accA.w;
    dst[256+4*lane+0] = accB.x; dst[256+4*lane+1] = accB.y;
    dst[256+4*lane+2] = accB.z; dst[256+4*lane+3] = accB.w;
    __syncthreads();

    float r0 = sred[0][tid]     + sred[1][tid]     + sred[2][tid]     + sred[3][tid];
    float r1 = sred[0][tid+256] + sred[1][tid+256] + sred[2][tid+256] + sred[3][tid+256];
    float* pout = partial_s + ((size_t)b*NCHUNK + chunk)*HD_;
    pout[tid]       = r0;
    pout[tid + 256] = r1;
}

// ---------------- fp16 routing pass: logits = b + u.vsum, softmax, accumulate c*u -----
// Lane mapping: lane loads 8 contiguous halves at 8*lane -> h = lane>>1, d0 = (lane&1)*8
__global__ __launch_bounds__(256) void pass16_kernel(const __half* __restrict__ u16,
                                                     const float* __restrict__ blog,
                                                     const float* __restrict__ vsum,
                                                     float* __restrict__ partial_s)
{
    const int b     = blockIdx.y;
    const int chunk = blockIdx.x;
    const int tid   = threadIdx.x;
    const int wave  = tid >> 6;
    const int lane  = tid & 63;
    const int h     = lane >> 1;          // 0..31
    const int d0    = (lane & 1) << 3;    // 0 or 8

    const float4 v0 = *(const float4*)(vsum + b*HD_ + h*D_ + d0);
    const float4 v1 = *(const float4*)(vsum + b*HD_ + h*D_ + d0 + 4);

    float acc[8] = {0.f,0.f,0.f,0.f,0.f,0.f,0.f,0.f};

    const int l0 = chunk*LCHUNK + wave*(LCHUNK/4);

    for (int j = 0; j < LCHUNK/4; ++j) {
        const int l = l0 + j;
        const size_t base = ((size_t)b*NL_ + l)*HD_;
        H8 x; x.u4 = *(const uint4*)(u16 + base + 8*lane);
        const float2 f0 = __half22float2(x.h2[0]);
        const float2 f1 = __half22float2(x.h2[1]);
        const float2 f2 = __half22float2(x.h2[2]);
        const float2 f3 = __half22float2(x.h2[3]);

        float dot = f0.x*v0.x + f0.y*v0.y + f1.x*v0.z + f1.y*v0.w
                  + f2.x*v1.x + f2.y*v1.y + f3.x*v1.z + f3.y*v1.w;
        dot += __shfl_xor(dot, 1);        // full d=16 dot (lane pair shares h)

        float la = blog[l*NH_ + h] + dot;

        // softmax over 32 h; values depend on lane>>1 -> skip off=1
        float m = la;
        #pragma unroll
        for (int off = 2; off < 64; off <<= 1) m = fmaxf(m, __shfl_xor(m, off));
        const float e = __expf(la - m);
        float ssum = e;
        #pragma unroll
        for (int off = 2; off < 64; off <<= 1) ssum += __shfl_xor(ssum, off);
        const float c = e * (2.0f / ssum);   // each h counted twice in ssum

        acc[0] += c*f0.x; acc[1] += c*f0.y; acc[2] += c*f1.x; acc[3] += c*f1.y;
        acc[4] += c*f2.x; acc[5] += c*f2.y; acc[6] += c*f3.x; acc[7] += c*f3.y;
    }

    __shared__ float sred[4][HD_];
    float* dst = &sred[wave][8*lane];
    #pragma unroll
    for (int k = 0; k < 8; ++k) dst[k] = acc[k];
    __syncthreads();

    float r0 = sred[0][tid]     + sred[1][tid]     + sred[2][tid]     + sred[3][tid];
    float r1 = sred[0][tid+256] + sred[1][tid+256] + sred[2][tid+256] + sred[3][tid+256];
    float* pout = partial_s + ((size_t)b*NCHUNK + chunk)*HD_;
    pout[tid]       = r0;
    pout[tid + 256] = r1;
}

// ---------------- fallback f32 routing pass (round-1 proven path) ---------------------
template<bool ADD_DOT>
__global__ __launch_bounds__(256) void pass_kernel(const float* __restrict__ u,
                                                   const float* __restrict__ blog,
                                                   const float* __restrict__ vsum,
                                                   float* __restrict__ partial_s)
{
    const int b     = blockIdx.y;
    const int chunk = blockIdx.x;
    const int tid   = threadIdx.x;
    const int wave  = tid >> 6;
    const int lane  = tid & 63;
    const int h0    = lane >> 2;
    const int h1    = h0 + 16;
    const int dq    = (lane & 3) << 2;

    float4 vA = {0.f,0.f,0.f,0.f}, vB = {0.f,0.f,0.f,0.f};
    if (ADD_DOT) {
        vA = *(const float4*)(vsum + b*HD_ + h0*D_ + dq);
        vB = *(const float4*)(vsum + b*HD_ + h1*D_ + dq);
    }

    float4 accA = {0.f,0.f,0.f,0.f};
    float4 accB = {0.f,0.f,0.f,0.f};
    const int l0 = chunk*LCHUNK + wave*(LCHUNK/4);

    for (int j = 0; j < LCHUNK/4; ++j) {
        const int l = l0 + j;
        const float* up = u + ((size_t)b*NL_ + l)*HD_;
        const float4 a  = *(const float4*)(up + 4*lane);
        const float4 bq = *(const float4*)(up + 256 + 4*lane);

        float la = blog[l*NH_ + h0];
        float lb = blog[l*NH_ + h1];

        if (ADD_DOT) {
            float da = a.x*vA.x + a.y*vA.y + a.z*vA.z + a.w*vA.w;
            float db = bq.x*vB.x + bq.y*vB.y + bq.z*vB.z + bq.w*vB.w;
            da += __shfl_xor(da, 1); da += __shfl_xor(da, 2);
            db += __shfl_xor(db, 1); db += __shfl_xor(db, 2);
            la += da; lb += db;
        }

        float m = fmaxf(la, lb);
        #pragma unroll
        for (int off = 4; off < 64; off <<= 1) m = fmaxf(m, __shfl_xor(m, off));
        const float ea = __expf(la - m);
        const float eb = __expf(lb - m);
        float ssum = ea + eb;
        #pragma unroll
        for (int off = 4; off < 64; off <<= 1) ssum += __shfl_xor(ssum, off);
        const float inv = 1.0f / ssum;
        const float ca = ea * inv;
        const float cb = eb * inv;

        accA.x += ca*a.x;  accA.y += ca*a.y;  accA.z += ca*a.z;  accA.w += ca*a.w;
        accB.x += cb*bq.x; accB.y += cb*bq.y; accB.z += cb*bq.z; accB.w += cb*bq.w;
    }

    __shared__ float sred[4][HD_];
    float* dst = &sred[wave][0];
    dst[4*lane+0]     = accA.x; dst[4*lane+1]     = accA.y;
    dst[4*lane+2]     = accA.z; dst[4*lane+3]     = accA.w;
    dst[256+4*lane+0] = accB.x; dst[256+4*lane+1] = accB.y;
    dst[256+4*lane+2] = accB.z; dst[256+4*lane+3] = accB.w;
    __syncthreads();

    float r0 = sred[0][tid]     + sred[1][tid]     + sred[2][tid]     + sred[3][tid];
    float r1 = sred[0][tid+256] + sred[1][tid+256] + sred[2][tid+256] + sred[3][tid+256];
    float* pout = partial_s + ((size_t)b*NCHUNK + chunk)*HD_;
    pout[tid]       = r0;
    pout[tid + 256] = r1;
}

// ---------------- squash: reduce chunks, Hinton squash, update vsum / write out -------
// MODE 0: vsum = v;  MODE 1: vsum += v;  MODE 2: out = v.
template<int MODE>
__global__ __launch_bounds__(512) void squash_kernel(const float* __restrict__ partial_s,
                                                     float* __restrict__ vsum,
                                                     float* __restrict__ out)
{
    const int b = blockIdx.x;
    const int t = threadIdx.x;            // t = h*16 + d
    const float* p = partial_s + (size_t)b*NCHUNK*HD_ + t;
    float s = 0.f;
    #pragma unroll
    for (int c = 0; c < NCHUNK; ++c) s += p[c*HD_];

    float sq = s*s;
    sq += __shfl_xor(sq, 1); sq += __shfl_xor(sq, 2);
    sq += __shfl_xor(sq, 4); sq += __shfl_xor(sq, 8);

    const float scale = sq / ((1.0f + sq) * sqrtf(sq + 1e-8f));
    const float v = s * scale;

    if (MODE == 0)      vsum[b*HD_ + t]  = v;
    else if (MODE == 1) vsum[b*HD_ + t] += v;
    else                out[b*HD_ + t]   = v;
}

extern "C" void kernel_launch(void* const* d_in, const int* in_sizes, int n_in,
                              void* d_out, int out_size, void* d_ws, size_t ws_size,
                              hipStream_t stream)
{
    const float* u    = (const float*)d_in[0];   // [64][2048][32][16]
    const float* blog = (const float*)d_in[1];   // [2048][32]
    float* out        = (float*)d_out;           // [64][32][16]

    // ws layout: [partials 4MB][vsum 128KB][u16 128MB]  (first 4.2MB = round-1 layout)
    float*  partial_s = (float*)d_ws;
    float*  vsum      = partial_s + (size_t)B_*NCHUNK*HD_;
    __half* u16       = (__half*)(vsum + (size_t)B_*HD_);
    const size_t need = ((size_t)B_*NCHUNK*HD_ + (size_t)B_*HD_)*sizeof(float)
                      + (size_t)B_*NL_*HD_*sizeof(__half);

    dim3 grid(NCHUNK, B_);
    dim3 block(256);

    if (ws_size >= need) {
        pass0_kernel<<<grid, block, 0, stream>>>(u, blog, u16, partial_s);
        squash_kernel<0><<<B_, 512, 0, stream>>>(partial_s, vsum, out);

        pass16_kernel<<<grid, block, 0, stream>>>(u16, blog, vsum, partial_s);
        squash_kernel<1><<<B_, 512, 0, stream>>>(partial_s, vsum, out);

        pass16_kernel<<<grid, block, 0, stream>>>(u16, blog, vsum, partial_s);
        squash_kernel<1><<<B_, 512, 0, stream>>>(partial_s, vsum, out);

        pass16_kernel<<<grid, block, 0, stream>>>(u16, blog, vsum, partial_s);
        squash_kernel<2><<<B_, 512, 0, stream>>>(partial_s, vsum, out);
    } else {
        pass_kernel<false><<<grid, block, 0, stream>>>(u, blog, vsum, partial_s);
        squash_kernel<0><<<B_, 512, 0, stream>>>(partial_s, vsum, out);

        pass_kernel<true><<<grid, block, 0, stream>>>(u, blog, vsum, partial_s);
        squash_kernel<1><<<B_, 512, 0, stream>>>(partial_s, vsum, out);

        pass_kernel<true><<<grid, block, 0, stream>>>(u, blog, vsum, partial_s);
        squash_kernel<1><<<B_, 512, 0, stream>>>(partial_s, vsum, out);

        pass_kernel<true><<<grid, block, 0, stream>>>(u, blog, vsum, partial_s);
        squash_kernel<2><<<B_, 512, 0, stream>>>(partial_s, vsum, out);
    }
}

// Round 4
// 155.322 us; speedup vs baseline: 1.2832x; 1.0318x over previous
//
#include <hip/hip_runtime.h>
#include <hip/hip_fp16.h>
#include <hip/hip_bf16.h>

// Problem constants (fixed by reference setup_inputs):
//   u_predict: [B=64][NL=2048][NH=32][D=16] f32  (256 MB)
//   b:         [NL=2048][NH=32] f32
//   out v:     [B=64][NH=32][D=16] f32
#define B_  64
#define NL_ 2048
#define NH_ 32
#define D_  16
#define HD_ 512              // NH_*D_
#define LCHUNK 64            // l's per block
#define NCHUNK (NL_/LCHUNK)  // 32

typedef float        f32x4 __attribute__((ext_vector_type(4)));
typedef unsigned int u32x4 __attribute__((ext_vector_type(4)));

union H8 { u32x4 u4; __half2 h2[4]; };
union F4 { f32x4 v;  float f[4]; };

// ---------------- pass 0: f32 read (non-temporal), c0 = softmax(b), fp16 copy emit ----
__global__ __launch_bounds__(256) void pass0_kernel(const float* __restrict__ u,
                                                    const float* __restrict__ blog,
                                                    __half* __restrict__ u16,
                                                    float* __restrict__ partial_s)
{
    const int b     = blockIdx.y;
    const int chunk = blockIdx.x;
    const int tid   = threadIdx.x;
    const int wave  = tid >> 6;
    const int lane  = tid & 63;
    const int h0    = lane >> 2;          // 0..15
    const int h1    = h0 + 16;

    float4 accA = {0.f,0.f,0.f,0.f};
    float4 accB = {0.f,0.f,0.f,0.f};

    const int l0 = chunk*LCHUNK + wave*(LCHUNK/4);

    for (int j = 0; j < LCHUNK/4; ++j) {
        const int l = l0 + j;
        const size_t base = ((size_t)b*NL_ + l)*HD_;
        // non-temporal: this 256 MB f32 stream is never re-read; keep it OUT of
        // L3 so the u16 array we are writing stays resident for passes 1-3.
        F4 a, bq;
        a.v  = __builtin_nontemporal_load((const f32x4*)(u + base + 4*lane));
        bq.v = __builtin_nontemporal_load((const f32x4*)(u + base + 256 + 4*lane));

        // emit fp16 copy (same [b][l][h][d] layout) — normal stores (want L3 residency)
        union { uint2 u2; __half2 h2[2]; } ha, hb;
        ha.h2[0] = __floats2half2_rn(a.f[0], a.f[1]);   ha.h2[1] = __floats2half2_rn(a.f[2], a.f[3]);
        hb.h2[0] = __floats2half2_rn(bq.f[0], bq.f[1]); hb.h2[1] = __floats2half2_rn(bq.f[2], bq.f[3]);
        *(uint2*)((__half*)u16 + base + 4*lane)       = ha.u2;
        *(uint2*)((__half*)u16 + base + 256 + 4*lane) = hb.u2;

        float la = blog[l*NH_ + h0];
        float lb = blog[l*NH_ + h1];

        // softmax over 32 h; values depend on lane>>2 only -> skip off=1,2
        float m = fmaxf(la, lb);
        #pragma unroll
        for (int off = 4; off < 64; off <<= 1) m = fmaxf(m, __shfl_xor(m, off));
        const float ea = __expf(la - m);
        const float eb = __expf(lb - m);
        float ssum = ea + eb;
        #pragma unroll
        for (int off = 4; off < 64; off <<= 1) ssum += __shfl_xor(ssum, off);
        const float inv = 1.0f / ssum;
        const float ca = ea * inv;
        const float cb = eb * inv;

        accA.x += ca*a.f[0];  accA.y += ca*a.f[1];  accA.z += ca*a.f[2];  accA.w += ca*a.f[3];
        accB.x += cb*bq.f[0]; accB.y += cb*bq.f[1]; accB.z += cb*bq.f[2]; accB.w += cb*bq.f[3];
    }

    __shared__ float sred[4][HD_];
    float* dst = &sred[wave][0];
    dst[4*lane+0]     = accA.x; dst[4*lane+1]     = accA.y;
    dst[4*lane+2]     = accA.z; dst[4*lane+3]     = accA.w;
    dst[256+4*lane+0] = accB.x; dst[256+4*lane+1] = accB.y;
    dst[256+4*lane+2] = accB.z; dst[256+4*lane+3] = accB.w;
    __syncthreads();

    float r0 = sred[0][tid]     + sred[1][tid]     + sred[2][tid]     + sred[3][tid];
    float r1 = sred[0][tid+256] + sred[1][tid+256] + sred[2][tid+256] + sred[3][tid+256];
    float* pout = partial_s + ((size_t)b*NCHUNK + chunk)*HD_;
    pout[tid]       = r0;
    pout[tid + 256] = r1;
}

// ---------------- fp16 routing pass: logits = b + u.vsum, softmax, accumulate c*u -----
// Lane mapping: lane loads 8 contiguous halves at 8*lane -> h = lane>>1, d0 = (lane&1)*8
// LAST=true: final read of u16 -> non-temporal loads (evict-first).
template<bool LAST>
__global__ __launch_bounds__(256) void pass16_kernel(const __half* __restrict__ u16,
                                                     const float* __restrict__ blog,
                                                     const float* __restrict__ vsum,
                                                     float* __restrict__ partial_s)
{
    const int b     = blockIdx.y;
    const int chunk = blockIdx.x;
    const int tid   = threadIdx.x;
    const int wave  = tid >> 6;
    const int lane  = tid & 63;
    const int h     = lane >> 1;          // 0..31
    const int d0    = (lane & 1) << 3;    // 0 or 8

    const float4 v0 = *(const float4*)(vsum + b*HD_ + h*D_ + d0);
    const float4 v1 = *(const float4*)(vsum + b*HD_ + h*D_ + d0 + 4);

    float acc[8] = {0.f,0.f,0.f,0.f,0.f,0.f,0.f,0.f};

    const int l0 = chunk*LCHUNK + wave*(LCHUNK/4);

    for (int j = 0; j < LCHUNK/4; ++j) {
        const int l = l0 + j;
        const size_t base = ((size_t)b*NL_ + l)*HD_;
        H8 x;
        if (LAST) x.u4 = __builtin_nontemporal_load((const u32x4*)(u16 + base + 8*lane));
        else      x.u4 = *(const u32x4*)(u16 + base + 8*lane);
        const float2 f0 = __half22float2(x.h2[0]);
        const float2 f1 = __half22float2(x.h2[1]);
        const float2 f2 = __half22float2(x.h2[2]);
        const float2 f3 = __half22float2(x.h2[3]);

        float dot = f0.x*v0.x + f0.y*v0.y + f1.x*v0.z + f1.y*v0.w
                  + f2.x*v1.x + f2.y*v1.y + f3.x*v1.z + f3.y*v1.w;
        dot += __shfl_xor(dot, 1);        // full d=16 dot (lane pair shares h)

        float la = blog[l*NH_ + h] + dot;

        // softmax over 32 h; values depend on lane>>1 -> skip off=1
        float m = la;
        #pragma unroll
        for (int off = 2; off < 64; off <<= 1) m = fmaxf(m, __shfl_xor(m, off));
        const float e = __expf(la - m);
        float ssum = e;
        #pragma unroll
        for (int off = 2; off < 64; off <<= 1) ssum += __shfl_xor(ssum, off);
        const float c = e * (2.0f / ssum);   // each h counted twice in ssum

        acc[0] += c*f0.x; acc[1] += c*f0.y; acc[2] += c*f1.x; acc[3] += c*f1.y;
        acc[4] += c*f2.x; acc[5] += c*f2.y; acc[6] += c*f3.x; acc[7] += c*f3.y;
    }

    __shared__ float sred[4][HD_];
    float* dst = &sred[wave][8*lane];
    #pragma unroll
    for (int k = 0; k < 8; ++k) dst[k] = acc[k];
    __syncthreads();

    float r0 = sred[0][tid]     + sred[1][tid]     + sred[2][tid]     + sred[3][tid];
    float r1 = sred[0][tid+256] + sred[1][tid+256] + sred[2][tid+256] + sred[3][tid+256];
    float* pout = partial_s + ((size_t)b*NCHUNK + chunk)*HD_;
    pout[tid]       = r0;
    pout[tid + 256] = r1;
}

// ---------------- fallback f32 routing pass (round-1 proven path) ---------------------
template<bool ADD_DOT>
__global__ __launch_bounds__(256) void pass_kernel(const float* __restrict__ u,
                                                   const float* __restrict__ blog,
                                                   const float* __restrict__ vsum,
                                                   float* __restrict__ partial_s)
{
    const int b     = blockIdx.y;
    const int chunk = blockIdx.x;
    const int tid   = threadIdx.x;
    const int wave  = tid >> 6;
    const int lane  = tid & 63;
    const int h0    = lane >> 2;
    const int h1    = h0 + 16;
    const int dq    = (lane & 3) << 2;

    float4 vA = {0.f,0.f,0.f,0.f}, vB = {0.f,0.f,0.f,0.f};
    if (ADD_DOT) {
        vA = *(const float4*)(vsum + b*HD_ + h0*D_ + dq);
        vB = *(const float4*)(vsum + b*HD_ + h1*D_ + dq);
    }

    float4 accA = {0.f,0.f,0.f,0.f};
    float4 accB = {0.f,0.f,0.f,0.f};
    const int l0 = chunk*LCHUNK + wave*(LCHUNK/4);

    for (int j = 0; j < LCHUNK/4; ++j) {
        const int l = l0 + j;
        const float* up = u + ((size_t)b*NL_ + l)*HD_;
        const float4 a  = *(const float4*)(up + 4*lane);
        const float4 bq = *(const float4*)(up + 256 + 4*lane);

        float la = blog[l*NH_ + h0];
        float lb = blog[l*NH_ + h1];

        if (ADD_DOT) {
            float da = a.x*vA.x + a.y*vA.y + a.z*vA.z + a.w*vA.w;
            float db = bq.x*vB.x + bq.y*vB.y + bq.z*vB.z + bq.w*vB.w;
            da += __shfl_xor(da, 1); da += __shfl_xor(da, 2);
            db += __shfl_xor(db, 1); db += __shfl_xor(db, 2);
            la += da; lb += db;
        }

        float m = fmaxf(la, lb);
        #pragma unroll
        for (int off = 4; off < 64; off <<= 1) m = fmaxf(m, __shfl_xor(m, off));
        const float ea = __expf(la - m);
        const float eb = __expf(lb - m);
        float ssum = ea + eb;
        #pragma unroll
        for (int off = 4; off < 64; off <<= 1) ssum += __shfl_xor(ssum, off);
        const float inv = 1.0f / ssum;
        const float ca = ea * inv;
        const float cb = eb * inv;

        accA.x += ca*a.x;  accA.y += ca*a.y;  accA.z += ca*a.z;  accA.w += ca*a.w;
        accB.x += cb*bq.x; accB.y += cb*bq.y; accB.z += cb*bq.z; accB.w += cb*bq.w;
    }

    __shared__ float sred[4][HD_];
    float* dst = &sred[wave][0];
    dst[4*lane+0]     = accA.x; dst[4*lane+1]     = accA.y;
    dst[4*lane+2]     = accA.z; dst[4*lane+3]     = accA.w;
    dst[256+4*lane+0] = accB.x; dst[256+4*lane+1] = accB.y;
    dst[256+4*lane+2] = accB.z; dst[256+4*lane+3] = accB.w;
    __syncthreads();

    float r0 = sred[0][tid]     + sred[1][tid]     + sred[2][tid]     + sred[3][tid];
    float r1 = sred[0][tid+256] + sred[1][tid+256] + sred[2][tid+256] + sred[3][tid+256];
    float* pout = partial_s + ((size_t)b*NCHUNK + chunk)*HD_;
    pout[tid]       = r0;
    pout[tid + 256] = r1;
}

// ---------------- squash: reduce chunks, Hinton squash, update vsum / write out -------
// MODE 0: vsum = v;  MODE 1: vsum += v;  MODE 2: out = v.
template<int MODE>
__global__ __launch_bounds__(512) void squash_kernel(const float* __restrict__ partial_s,
                                                     float* __restrict__ vsum,
                                                     float* __restrict__ out)
{
    const int b = blockIdx.x;
    const int t = threadIdx.x;            // t = h*16 + d
    const float* p = partial_s + (size_t)b*NCHUNK*HD_ + t;
    float s = 0.f;
    #pragma unroll
    for (int c = 0; c < NCHUNK; ++c) s += p[c*HD_];

    float sq = s*s;
    sq += __shfl_xor(sq, 1); sq += __shfl_xor(sq, 2);
    sq += __shfl_xor(sq, 4); sq += __shfl_xor(sq, 8);

    const float scale = sq / ((1.0f + sq) * sqrtf(sq + 1e-8f));
    const float v = s * scale;

    if (MODE == 0)      vsum[b*HD_ + t]  = v;
    else if (MODE == 1) vsum[b*HD_ + t] += v;
    else                out[b*HD_ + t]   = v;
}

extern "C" void kernel_launch(void* const* d_in, const int* in_sizes, int n_in,
                              void* d_out, int out_size, void* d_ws, size_t ws_size,
                              hipStream_t stream)
{
    const float* u    = (const float*)d_in[0];   // [64][2048][32][16]
    const float* blog = (const float*)d_in[1];   // [2048][32]
    float* out        = (float*)d_out;           // [64][32][16]

    // ws layout: [partials 4MB][vsum 128KB][u16 128MB]
    float*  partial_s = (float*)d_ws;
    float*  vsum      = partial_s + (size_t)B_*NCHUNK*HD_;
    __half* u16       = (__half*)(vsum + (size_t)B_*HD_);
    const size_t need = ((size_t)B_*NCHUNK*HD_ + (size_t)B_*HD_)*sizeof(float)
                      + (size_t)B_*NL_*HD_*sizeof(__half);

    dim3 grid(NCHUNK, B_);
    dim3 block(256);

    if (ws_size >= need) {
        pass0_kernel<<<grid, block, 0, stream>>>(u, blog, u16, partial_s);
        squash_kernel<0><<<B_, 512, 0, stream>>>(partial_s, vsum, out);

        pass16_kernel<false><<<grid, block, 0, stream>>>(u16, blog, vsum, partial_s);
        squash_kernel<1><<<B_, 512, 0, stream>>>(partial_s, vsum, out);

        pass16_kernel<false><<<grid, block, 0, stream>>>(u16, blog, vsum, partial_s);
        squash_kernel<1><<<B_, 512, 0, stream>>>(partial_s, vsum, out);

        pass16_kernel<true><<<grid, block, 0, stream>>>(u16, blog, vsum, partial_s);
        squash_kernel<2><<<B_, 512, 0, stream>>>(partial_s, vsum, out);
    } else {
        pass_kernel<false><<<grid, block, 0, stream>>>(u, blog, vsum, partial_s);
        squash_kernel<0><<<B_, 512, 0, stream>>>(partial_s, vsum, out);

        pass_kernel<true><<<grid, block, 0, stream>>>(u, blog, vsum, partial_s);
        squash_kernel<1><<<B_, 512, 0, stream>>>(partial_s, vsum, out);

        pass_kernel<true><<<grid, block, 0, stream>>>(u, blog, vsum, partial_s);
        squash_kernel<1><<<B_, 512, 0, stream>>>(partial_s, vsum, out);

        pass_kernel<true><<<grid, block, 0, stream>>>(u, blog, vsum, partial_s);
        squash_kernel<2><<<B_, 512, 0, stream>>>(partial_s, vsum, out);
    }
}

// Round 5
// 155.057 us; speedup vs baseline: 1.2854x; 1.0017x over previous
//
#include <hip/hip_runtime.h>
#include <hip/hip_fp16.h>
#include <hip/hip_bf16.h>

// Problem constants (fixed by reference setup_inputs):
//   u_predict: [B=64][NL=2048][NH=32][D=16] f32  (256 MB)
//   b:         [NL=2048][NH=32] f32
//   out v:     [B=64][NH=32][D=16] f32
#define B_  64
#define NL_ 2048
#define NH_ 32
#define D_  16
#define HD_ 512              // NH_*D_
#define LCHUNK 64            // l's per block
#define NCHUNK (NL_/LCHUNK)  // 32

typedef float        f32x4 __attribute__((ext_vector_type(4)));
typedef unsigned int u32x4 __attribute__((ext_vector_type(4)));

union H8 { u32x4 u4; __half2 h2[4]; };
union F4 { f32x4 v;  float f[4]; };

// ---------------- c0 kernel: c0 = softmax(blog) over h (u-independent) ---------------
__global__ __launch_bounds__(256) void c0_kernel(const float* __restrict__ blog,
                                                 float* __restrict__ c0)
{
    const int tid = threadIdx.x;
    const int l   = blockIdx.x*8 + (tid >> 5);
    const int h   = tid & 31;
    float x = blog[l*NH_ + h];
    float m = x;
    #pragma unroll
    for (int off = 1; off < 32; off <<= 1) m = fmaxf(m, __shfl_xor(m, off));
    float e = __expf(x - m);
    float s = e;
    #pragma unroll
    for (int off = 1; off < 32; off <<= 1) s += __shfl_xor(s, off);
    c0[l*NH_ + h] = e / s;
}

// ---------------- pass 0: f32 read (nt), weighted sum with precomputed c0, emit fp16 --
__global__ __launch_bounds__(256) void pass0_kernel(const float* __restrict__ u,
                                                    const float* __restrict__ c0,
                                                    __half* __restrict__ u16,
                                                    float* __restrict__ partial_s)
{
    const int b     = blockIdx.y;
    const int chunk = blockIdx.x;
    const int tid   = threadIdx.x;
    const int wave  = tid >> 6;
    const int lane  = tid & 63;
    const int h0    = lane >> 2;          // 0..15
    const int h1    = h0 + 16;

    float4 accA = {0.f,0.f,0.f,0.f};
    float4 accB = {0.f,0.f,0.f,0.f};

    const int l0 = chunk*LCHUNK + wave*(LCHUNK/4);

    for (int j = 0; j < LCHUNK/4; ++j) {
        const int l = l0 + j;
        const size_t base = ((size_t)b*NL_ + l)*HD_;
        // non-temporal: the 256 MB f32 stream is never re-read.
        F4 a, bq;
        a.v  = __builtin_nontemporal_load((const f32x4*)(u + base + 4*lane));
        bq.v = __builtin_nontemporal_load((const f32x4*)(u + base + 256 + 4*lane));

        // emit fp16 copy (same [b][l][h][d] layout)
        union { uint2 u2; __half2 h2[2]; } ha, hb;
        ha.h2[0] = __floats2half2_rn(a.f[0], a.f[1]);   ha.h2[1] = __floats2half2_rn(a.f[2], a.f[3]);
        hb.h2[0] = __floats2half2_rn(bq.f[0], bq.f[1]); hb.h2[1] = __floats2half2_rn(bq.f[2], bq.f[3]);
        *(uint2*)((__half*)u16 + base + 4*lane)       = ha.u2;
        *(uint2*)((__half*)u16 + base + 256 + 4*lane) = hb.u2;

        const float ca = c0[l*NH_ + h0];
        const float cb = c0[l*NH_ + h1];

        accA.x += ca*a.f[0];  accA.y += ca*a.f[1];  accA.z += ca*a.f[2];  accA.w += ca*a.f[3];
        accB.x += cb*bq.f[0]; accB.y += cb*bq.f[1]; accB.z += cb*bq.f[2]; accB.w += cb*bq.f[3];
    }

    __shared__ float sred[4][HD_];
    float* dst = &sred[wave][0];
    dst[4*lane+0]     = accA.x; dst[4*lane+1]     = accA.y;
    dst[4*lane+2]     = accA.z; dst[4*lane+3]     = accA.w;
    dst[256+4*lane+0] = accB.x; dst[256+4*lane+1] = accB.y;
    dst[256+4*lane+2] = accB.z; dst[256+4*lane+3] = accB.w;
    __syncthreads();

    float r0 = sred[0][tid]     + sred[1][tid]     + sred[2][tid]     + sred[3][tid];
    float r1 = sred[0][tid+256] + sred[1][tid+256] + sred[2][tid+256] + sred[3][tid+256];
    float* pout = partial_s + ((size_t)b*NCHUNK + chunk)*HD_;
    pout[tid]       = r0;
    pout[tid + 256] = r1;
}

// ---------------- fp16 routing pass: lane owns full h (16 d's), 2 l's per wave-iter ---
// lane: hh = lane&31 (h), lpar = lane>>5 (which l of the pair). Dot is fully in-lane;
// softmax sum = 5 shfl_xor within the 32-lane group; no max-subtract (clamped exp).
template<bool LAST>
__global__ __launch_bounds__(256) void pass16_kernel(const __half* __restrict__ u16,
                                                     const float* __restrict__ blog,
                                                     const float* __restrict__ vsum,
                                                     float* __restrict__ partial_s)
{
    const int b     = blockIdx.y;
    const int chunk = blockIdx.x;
    const int tid   = threadIdx.x;
    const int wave  = tid >> 6;
    const int lane  = tid & 63;
    const int hh    = lane & 31;
    const int lpar  = lane >> 5;

    // this lane's v-sum vector (16 floats, broadcast across lanes with same hh)
    float vs[16];
    #pragma unroll
    for (int q = 0; q < 4; ++q) {
        const float4 t = *(const float4*)(vsum + b*HD_ + hh*D_ + 4*q);
        vs[4*q+0] = t.x; vs[4*q+1] = t.y; vs[4*q+2] = t.z; vs[4*q+3] = t.w;
    }

    float acc[16];
    #pragma unroll
    for (int d = 0; d < 16; ++d) acc[d] = 0.f;

    const int lbase = chunk*LCHUNK + wave*(LCHUNK/4);   // 16 l's per wave

    for (int j = 0; j < LCHUNK/8; ++j) {                // 8 iters, 2 l's each
        const int l = lbase + 2*j + lpar;
        const size_t base = ((size_t)b*NL_ + l)*HD_ + hh*D_;
        H8 x0, x1;
        if (LAST) {
            x0.u4 = __builtin_nontemporal_load((const u32x4*)(u16 + base));
            x1.u4 = __builtin_nontemporal_load((const u32x4*)(u16 + base + 8));
        } else {
            x0.u4 = *(const u32x4*)(u16 + base);
            x1.u4 = *(const u32x4*)(u16 + base + 8);
        }
        float f[16];
        #pragma unroll
        for (int q = 0; q < 4; ++q) {
            const float2 t0 = __half22float2(x0.h2[q]);
            const float2 t1 = __half22float2(x1.h2[q]);
            f[2*q+0] = t0.x; f[2*q+1] = t0.y;
            f[8+2*q+0] = t1.x; f[8+2*q+1] = t1.y;
        }

        float dot = 0.f;
        #pragma unroll
        for (int d = 0; d < 16; ++d) dot = __fmaf_rn(f[d], vs[d], dot);

        const float la = fminf(blog[l*NH_ + hh] + dot, 80.f);
        const float e  = __expf(la);
        float ssum = e;
        #pragma unroll
        for (int off = 1; off < 32; off <<= 1) ssum += __shfl_xor(ssum, off);
        const float c = e / ssum;

        #pragma unroll
        for (int d = 0; d < 16; ++d) acc[d] = __fmaf_rn(c, f[d], acc[d]);
    }

    // block reduce: sred[wave][lpar][hh][d]
    __shared__ float sred[4][2][NH_][D_];
    float* dst = &sred[wave][lpar][hh][0];
    #pragma unroll
    for (int q = 0; q < 4; ++q) {
        float4 t = { acc[4*q+0], acc[4*q+1], acc[4*q+2], acc[4*q+3] };
        *(float4*)(dst + 4*q) = t;
    }
    __syncthreads();

    const float* sp = &sred[0][0][0][0];
    float r0 = 0.f, r1 = 0.f;
    #pragma unroll
    for (int w = 0; w < 4; ++w) {
        #pragma unroll
        for (int p = 0; p < 2; ++p) {
            r0 += sp[w*1024 + p*512 + tid];
            r1 += sp[w*1024 + p*512 + tid + 256];
        }
    }
    float* pout = partial_s + ((size_t)b*NCHUNK + chunk)*HD_;
    pout[tid]       = r0;
    pout[tid + 256] = r1;
}

// ---------------- fallback f32 routing pass (round-1 proven path) ---------------------
template<bool ADD_DOT>
__global__ __launch_bounds__(256) void pass_kernel(const float* __restrict__ u,
                                                   const float* __restrict__ blog,
                                                   const float* __restrict__ vsum,
                                                   float* __restrict__ partial_s)
{
    const int b     = blockIdx.y;
    const int chunk = blockIdx.x;
    const int tid   = threadIdx.x;
    const int wave  = tid >> 6;
    const int lane  = tid & 63;
    const int h0    = lane >> 2;
    const int h1    = h0 + 16;
    const int dq    = (lane & 3) << 2;

    float4 vA = {0.f,0.f,0.f,0.f}, vB = {0.f,0.f,0.f,0.f};
    if (ADD_DOT) {
        vA = *(const float4*)(vsum + b*HD_ + h0*D_ + dq);
        vB = *(const float4*)(vsum + b*HD_ + h1*D_ + dq);
    }

    float4 accA = {0.f,0.f,0.f,0.f};
    float4 accB = {0.f,0.f,0.f,0.f};
    const int l0 = chunk*LCHUNK + wave*(LCHUNK/4);

    for (int j = 0; j < LCHUNK/4; ++j) {
        const int l = l0 + j;
        const float* up = u + ((size_t)b*NL_ + l)*HD_;
        const float4 a  = *(const float4*)(up + 4*lane);
        const float4 bq = *(const float4*)(up + 256 + 4*lane);

        float la = blog[l*NH_ + h0];
        float lb = blog[l*NH_ + h1];

        if (ADD_DOT) {
            float da = a.x*vA.x + a.y*vA.y + a.z*vA.z + a.w*vA.w;
            float db = bq.x*vB.x + bq.y*vB.y + bq.z*vB.z + bq.w*vB.w;
            da += __shfl_xor(da, 1); da += __shfl_xor(da, 2);
            db += __shfl_xor(db, 1); db += __shfl_xor(db, 2);
            la += da; lb += db;
        }

        float m = fmaxf(la, lb);
        #pragma unroll
        for (int off = 4; off < 64; off <<= 1) m = fmaxf(m, __shfl_xor(m, off));
        const float ea = __expf(la - m);
        const float eb = __expf(lb - m);
        float ssum = ea + eb;
        #pragma unroll
        for (int off = 4; off < 64; off <<= 1) ssum += __shfl_xor(ssum, off);
        const float inv = 1.0f / ssum;
        const float ca = ea * inv;
        const float cb = eb * inv;

        accA.x += ca*a.x;  accA.y += ca*a.y;  accA.z += ca*a.z;  accA.w += ca*a.w;
        accB.x += cb*bq.x; accB.y += cb*bq.y; accB.z += cb*bq.z; accB.w += cb*bq.w;
    }

    __shared__ float sred[4][HD_];
    float* dst = &sred[wave][0];
    dst[4*lane+0]     = accA.x; dst[4*lane+1]     = accA.y;
    dst[4*lane+2]     = accA.z; dst[4*lane+3]     = accA.w;
    dst[256+4*lane+0] = accB.x; dst[256+4*lane+1] = accB.y;
    dst[256+4*lane+2] = accB.z; dst[256+4*lane+3] = accB.w;
    __syncthreads();

    float r0 = sred[0][tid]     + sred[1][tid]     + sred[2][tid]     + sred[3][tid];
    float r1 = sred[0][tid+256] + sred[1][tid+256] + sred[2][tid+256] + sred[3][tid+256];
    float* pout = partial_s + ((size_t)b*NCHUNK + chunk)*HD_;
    pout[tid]       = r0;
    pout[tid + 256] = r1;
}

// ---------------- squash: reduce chunks, Hinton squash, update vsum / write out -------
// MODE 0: vsum = v;  MODE 1: vsum += v;  MODE 2: out = v.
template<int MODE>
__global__ __launch_bounds__(512) void squash_kernel(const float* __restrict__ partial_s,
                                                     float* __restrict__ vsum,
                                                     float* __restrict__ out)
{
    const int b = blockIdx.x;
    const int t = threadIdx.x;            // t = h*16 + d
    const float* p = partial_s + (size_t)b*NCHUNK*HD_ + t;
    float s = 0.f;
    #pragma unroll
    for (int c = 0; c < NCHUNK; ++c) s += p[c*HD_];

    float sq = s*s;
    sq += __shfl_xor(sq, 1); sq += __shfl_xor(sq, 2);
    sq += __shfl_xor(sq, 4); sq += __shfl_xor(sq, 8);

    const float scale = sq / ((1.0f + sq) * sqrtf(sq + 1e-8f));
    const float v = s * scale;

    if (MODE == 0)      vsum[b*HD_ + t]  = v;
    else if (MODE == 1) vsum[b*HD_ + t] += v;
    else                out[b*HD_ + t]   = v;
}

extern "C" void kernel_launch(void* const* d_in, const int* in_sizes, int n_in,
                              void* d_out, int out_size, void* d_ws, size_t ws_size,
                              hipStream_t stream)
{
    const float* u    = (const float*)d_in[0];   // [64][2048][32][16]
    const float* blog = (const float*)d_in[1];   // [2048][32]
    float* out        = (float*)d_out;           // [64][32][16]

    // ws layout: [partials 4MB][vsum 128KB][c0 256KB][u16 128MB]
    float*  partial_s = (float*)d_ws;
    float*  vsum      = partial_s + (size_t)B_*NCHUNK*HD_;
    float*  c0        = vsum + (size_t)B_*HD_;
    __half* u16       = (__half*)(c0 + (size_t)NL_*NH_);
    const size_t need = ((size_t)B_*NCHUNK*HD_ + (size_t)B_*HD_ + (size_t)NL_*NH_)*sizeof(float)
                      + (size_t)B_*NL_*HD_*sizeof(__half);

    dim3 grid(NCHUNK, B_);
    dim3 block(256);

    if (ws_size >= need) {
        c0_kernel<<<NL_/8, 256, 0, stream>>>(blog, c0);
        pass0_kernel<<<grid, block, 0, stream>>>(u, c0, u16, partial_s);
        squash_kernel<0><<<B_, 512, 0, stream>>>(partial_s, vsum, out);

        pass16_kernel<false><<<grid, block, 0, stream>>>(u16, blog, vsum, partial_s);
        squash_kernel<1><<<B_, 512, 0, stream>>>(partial_s, vsum, out);

        pass16_kernel<false><<<grid, block, 0, stream>>>(u16, blog, vsum, partial_s);
        squash_kernel<1><<<B_, 512, 0, stream>>>(partial_s, vsum, out);

        pass16_kernel<true><<<grid, block, 0, stream>>>(u16, blog, vsum, partial_s);
        squash_kernel<2><<<B_, 512, 0, stream>>>(partial_s, vsum, out);
    } else {
        pass_kernel<false><<<grid, block, 0, stream>>>(u, blog, vsum, partial_s);
        squash_kernel<0><<<B_, 512, 0, stream>>>(partial_s, vsum, out);

        pass_kernel<true><<<grid, block, 0, stream>>>(u, blog, vsum, partial_s);
        squash_kernel<1><<<B_, 512, 0, stream>>>(partial_s, vsum, out);

        pass_kernel<true><<<grid, block, 0, stream>>>(u, blog, vsum, partial_s);
        squash_kernel<1><<<B_, 512, 0, stream>>>(partial_s, vsum, out);

        pass_kernel<true><<<grid, block, 0, stream>>>(u, blog, vsum, partial_s);
        squash_kernel<2><<<B_, 512, 0, stream>>>(partial_s, vsum, out);
    }
}